// Round 2
// baseline (539.700 us; speedup 1.0000x reference)
//
#include <hip/hip_runtime.h>
#include <hip/hip_bf16.h>

// GraphSAGE 2-layer + classifier, CSR pull aggregation.
// N=100000, E=1600000, C=HID=64.
// ws (total ~19.5 MB, checked against ws_size):
//   deg(N int) | cursor(N int) | offs(N+1 int) | bsum(nb int) | csr(E int) | h1(N*64 bf16)

#define C 64

static inline size_t align256(size_t x) { return (x + 255) & ~(size_t)255; }

__global__ void count_kernel(const int* __restrict__ ei, int* __restrict__ deg, int E) {
    int stride = gridDim.x * blockDim.x;
    for (int e = blockIdx.x * blockDim.x + threadIdx.x; e < E; e += stride)
        atomicAdd(&deg[ei[E + e]], 1);      // row 1 = dst
}

// Phase 1: per-block (1024) exclusive scan; emit block total.
__global__ __launch_bounds__(1024) void scan1_kernel(const int* __restrict__ deg,
                                                     int* __restrict__ offs,
                                                     int* __restrict__ bsum, int n) {
    __shared__ int wsum[16];
    const int lane = threadIdx.x & 63;
    const int wid  = threadIdx.x >> 6;
    int i = blockIdx.x * 1024 + threadIdx.x;
    int v = (i < n) ? deg[i] : 0;
    int s = v;
    #pragma unroll
    for (int off = 1; off < 64; off <<= 1) {
        int t = __shfl_up(s, off, 64);
        if (lane >= off) s += t;
    }
    if (lane == 63) wsum[wid] = s;
    __syncthreads();
    int wprefix = 0;
    for (int w = 0; w < wid; ++w) wprefix += wsum[w];
    if (i < n) offs[i] = wprefix + (s - v);
    if (threadIdx.x == 0) {
        int tot = 0;
        #pragma unroll
        for (int w = 0; w < 16; ++w) tot += wsum[w];
        bsum[blockIdx.x] = tot;
    }
}

// Phase 2: single block scans the <=1024 block sums; writes offs[n]=total.
__global__ __launch_bounds__(1024) void scan2_kernel(int* __restrict__ bsum,
                                                     int* __restrict__ offs, int nb, int n) {
    __shared__ int wsum[16];
    const int lane = threadIdx.x & 63;
    const int wid  = threadIdx.x >> 6;
    int v = ((int)threadIdx.x < nb) ? bsum[threadIdx.x] : 0;
    int s = v;
    #pragma unroll
    for (int off = 1; off < 64; off <<= 1) {
        int t = __shfl_up(s, off, 64);
        if (lane >= off) s += t;
    }
    if (lane == 63) wsum[wid] = s;
    __syncthreads();
    int wprefix = 0;
    for (int w = 0; w < wid; ++w) wprefix += wsum[w];
    if ((int)threadIdx.x < nb) bsum[threadIdx.x] = wprefix + (s - v);
    if (threadIdx.x == 0) {
        int tot = 0;
        #pragma unroll
        for (int w = 0; w < 16; ++w) tot += wsum[w];
        offs[n] = tot;
    }
}

// Phase 3: add block prefixes back.
__global__ void scan3_kernel(int* __restrict__ offs, const int* __restrict__ bsum, int n) {
    int i = blockIdx.x * blockDim.x + threadIdx.x;
    if (i < n) offs[i] += bsum[i >> 10];
}

__global__ void fill_kernel(const int* __restrict__ ei, const int* __restrict__ offs,
                            int* __restrict__ cursor, int* __restrict__ csr, int E) {
    int stride = gridDim.x * blockDim.x;
    for (int e = blockIdx.x * blockDim.x + threadIdx.x; e < E; e += stride) {
        int d = ei[E + e];
        int p = atomicAdd(&cursor[d], 1);
        csr[offs[d] + p] = ei[e];           // row 0 = src
    }
}

__device__ inline float ldf(const float* p) { return *p; }
__device__ inline float ldf(const __hip_bfloat16* p) { return __bfloat162float(*p); }

// One wave per node, lane = channel. 256 threads = 4 nodes/block.
// h = relu(mean_{j in N(i)} X_j @ Wl + bl + X_i @ Wr)
// FINAL=0: out is bf16 [N,64].  FINAL=1: out is f32 [N] = h . Wc + bc.
template <typename TIN, bool FINAL>
__global__ __launch_bounds__(256) void sage_kernel(
    const TIN* __restrict__ X, const int* __restrict__ csr,
    const int* __restrict__ offs,
    const float* __restrict__ Wl, const float* __restrict__ bl,
    const float* __restrict__ Wr, const float* __restrict__ Wc,
    const float* __restrict__ bc, void* __restrict__ outp, int n)
{
    const int lane = threadIdx.x & 63;
    const int wid  = threadIdx.x >> 6;
    const int node = blockIdx.x * 4 + wid;
    __shared__ float smem[4][2][C];

    bool active = (node < n);
    if (active) {
        int start = offs[node];
        int dcount = offs[node + 1] - start;
        float acc = 0.f;
        int k = 0;
        for (; k + 4 <= dcount; k += 4) {
            int s0 = csr[start + k + 0];
            int s1 = csr[start + k + 1];
            int s2 = csr[start + k + 2];
            int s3 = csr[start + k + 3];
            acc += ldf(&X[(size_t)s0 * C + lane]);
            acc += ldf(&X[(size_t)s1 * C + lane]);
            acc += ldf(&X[(size_t)s2 * C + lane]);
            acc += ldf(&X[(size_t)s3 * C + lane]);
        }
        for (; k < dcount; ++k)
            acc += ldf(&X[(size_t)csr[start + k] * C + lane]);
        smem[wid][0][lane] = acc * (1.0f / fmaxf((float)dcount, 1.0f));
        smem[wid][1][lane] = ldf(&X[(size_t)node * C + lane]);
    }
    __syncthreads();
    if (!active) return;

    float o = bl[lane];
    #pragma unroll 8
    for (int kk = 0; kk < C; ++kk) {
        o += smem[wid][0][kk] * Wl[kk * C + lane];
        o += smem[wid][1][kk] * Wr[kk * C + lane];
    }
    o = fmaxf(o, 0.f);

    if (!FINAL) {
        ((__hip_bfloat16*)outp)[(size_t)node * C + lane] = __float2bfloat16(o);
    } else {
        float p = o * Wc[lane];
        #pragma unroll
        for (int off = 32; off >= 1; off >>= 1) p += __shfl_xor(p, off, 64);
        if (lane == 0) ((float*)outp)[node] = p + bc[0];
    }
}

extern "C" void kernel_launch(void* const* d_in, const int* in_sizes, int n_in,
                              void* d_out, int out_size, void* d_ws, size_t ws_size,
                              hipStream_t stream) {
    const float* x   = (const float*)d_in[0];
    const int*   ei  = (const int*)d_in[1];
    const float* Wl1 = (const float*)d_in[2];
    const float* bl1 = (const float*)d_in[3];
    const float* Wr1 = (const float*)d_in[4];
    const float* Wl2 = (const float*)d_in[5];
    const float* bl2 = (const float*)d_in[6];
    const float* Wr2 = (const float*)d_in[7];
    const float* Wc  = (const float*)d_in[8];
    const float* bc  = (const float*)d_in[9];
    float* out = (float*)d_out;

    const int N = in_sizes[0] / C;
    const int E = in_sizes[1] / 2;
    const int nb = (N + 1023) / 1024;

    char* ws = (char*)d_ws;
    size_t off = 0;
    int* deg    = (int*)(ws + off); off += align256((size_t)N * 4);
    int* cursor = (int*)(ws + off); off += align256((size_t)N * 4);
    int* offs   = (int*)(ws + off); off += align256((size_t)(N + 1) * 4);
    int* bsum   = (int*)(ws + off); off += align256((size_t)nb * 4);
    int* csr    = (int*)(ws + off); off += align256((size_t)E * 4);
    __hip_bfloat16* h1 = (__hip_bfloat16*)(ws + off); off += align256((size_t)N * C * 2);

    if (off > ws_size) return;   // fail loudly (poisoned out) rather than corrupt neighbors

    // zero deg + cursor (contiguous leading regions)
    hipMemsetAsync(d_ws, 0, align256((size_t)N * 4) + (size_t)N * 4, stream);

    const int blk = 256;
    const int edge_grid = 2048;
    count_kernel<<<edge_grid, blk, 0, stream>>>(ei, deg, E);
    scan1_kernel<<<nb, 1024, 0, stream>>>(deg, offs, bsum, N);
    scan2_kernel<<<1, 1024, 0, stream>>>(bsum, offs, nb, N);
    scan3_kernel<<<(N + 255) / 256, 256, 0, stream>>>(offs, bsum, N);
    fill_kernel<<<edge_grid, blk, 0, stream>>>(ei, offs, cursor, csr, E);

    const int node_grid = (N + 3) / 4;
    sage_kernel<float, false><<<node_grid, blk, 0, stream>>>(
        x, csr, offs, Wl1, bl1, Wr1, nullptr, nullptr, h1, N);
    sage_kernel<__hip_bfloat16, true><<<node_grid, blk, 0, stream>>>(
        h1, csr, offs, Wl2, bl2, Wr2, Wc, bc, out, N);
}

// Round 3
// 506.283 us; speedup vs baseline: 1.0660x; 1.0660x over previous
//
#include <hip/hip_runtime.h>
#include <hip/hip_bf16.h>

// GraphSAGE 2-layer + classifier, CSR pull aggregation, 16-deep gather ILP.
// N=100000, E=1600000, C=HID=64.
// ws: deg(N) | cursor(N) | offs(N+1) | bsum(nb) | csr(E) | h1(N*64 bf16) | [xb(N*64 bf16) if fits]

#define C 64

static inline size_t align256(size_t x) { return (x + 255) & ~(size_t)255; }

__global__ void count_kernel(const int* __restrict__ ei, int* __restrict__ deg, int E) {
    const int4* d4 = (const int4*)(ei + E);        // row 1 = dst
    int nE4 = E >> 2;
    int stride = gridDim.x * blockDim.x;
    for (int i = blockIdx.x * blockDim.x + threadIdx.x; i < nE4; i += stride) {
        int4 d = d4[i];
        atomicAdd(&deg[d.x], 1);
        atomicAdd(&deg[d.y], 1);
        atomicAdd(&deg[d.z], 1);
        atomicAdd(&deg[d.w], 1);
    }
    for (int e = (nE4 << 2) + blockIdx.x * blockDim.x + threadIdx.x; e < E; e += stride)
        atomicAdd(&deg[ei[E + e]], 1);
}

// Phase 1: per-block (1024) exclusive scan; emit block total.
__global__ __launch_bounds__(1024) void scan1_kernel(const int* __restrict__ deg,
                                                     int* __restrict__ offs,
                                                     int* __restrict__ bsum, int n) {
    __shared__ int wsum[16];
    const int lane = threadIdx.x & 63;
    const int wid  = threadIdx.x >> 6;
    int i = blockIdx.x * 1024 + threadIdx.x;
    int v = (i < n) ? deg[i] : 0;
    int s = v;
    #pragma unroll
    for (int off = 1; off < 64; off <<= 1) {
        int t = __shfl_up(s, off, 64);
        if (lane >= off) s += t;
    }
    if (lane == 63) wsum[wid] = s;
    __syncthreads();
    int wprefix = 0;
    for (int w = 0; w < wid; ++w) wprefix += wsum[w];
    if (i < n) offs[i] = wprefix + (s - v);
    if (threadIdx.x == 0) {
        int tot = 0;
        #pragma unroll
        for (int w = 0; w < 16; ++w) tot += wsum[w];
        bsum[blockIdx.x] = tot;
    }
}

// Phase 2: single block scans the <=1024 block sums; writes offs[n]=total.
__global__ __launch_bounds__(1024) void scan2_kernel(int* __restrict__ bsum,
                                                     int* __restrict__ offs, int nb, int n) {
    __shared__ int wsum[16];
    const int lane = threadIdx.x & 63;
    const int wid  = threadIdx.x >> 6;
    int v = ((int)threadIdx.x < nb) ? bsum[threadIdx.x] : 0;
    int s = v;
    #pragma unroll
    for (int off = 1; off < 64; off <<= 1) {
        int t = __shfl_up(s, off, 64);
        if (lane >= off) s += t;
    }
    if (lane == 63) wsum[wid] = s;
    __syncthreads();
    int wprefix = 0;
    for (int w = 0; w < wid; ++w) wprefix += wsum[w];
    if ((int)threadIdx.x < nb) bsum[threadIdx.x] = wprefix + (s - v);
    if (threadIdx.x == 0) {
        int tot = 0;
        #pragma unroll
        for (int w = 0; w < 16; ++w) tot += wsum[w];
        offs[n] = tot;
    }
}

// Phase 3: add block prefixes back.
__global__ void scan3_kernel(int* __restrict__ offs, const int* __restrict__ bsum, int n) {
    int i = blockIdx.x * blockDim.x + threadIdx.x;
    if (i < n) offs[i] += bsum[i >> 10];
}

__global__ void fill_kernel(const int* __restrict__ ei, const int* __restrict__ offs,
                            int* __restrict__ cursor, int* __restrict__ csr, int E) {
    const int4* s4 = (const int4*)ei;
    const int4* d4 = (const int4*)(ei + E);
    int nE4 = E >> 2;
    int stride = gridDim.x * blockDim.x;
    for (int i = blockIdx.x * blockDim.x + threadIdx.x; i < nE4; i += stride) {
        int4 s = s4[i];
        int4 d = d4[i];
        int p;
        p = atomicAdd(&cursor[d.x], 1); csr[offs[d.x] + p] = s.x;
        p = atomicAdd(&cursor[d.y], 1); csr[offs[d.y] + p] = s.y;
        p = atomicAdd(&cursor[d.z], 1); csr[offs[d.z] + p] = s.z;
        p = atomicAdd(&cursor[d.w], 1); csr[offs[d.w] + p] = s.w;
    }
    for (int e = (nE4 << 2) + blockIdx.x * blockDim.x + threadIdx.x; e < E; e += stride) {
        int d = ei[E + e];
        int p = atomicAdd(&cursor[d], 1);
        csr[offs[d] + p] = ei[e];
    }
}

// f32 [N*C] -> bf16 [N*C]
__global__ void cvt_kernel(const float* __restrict__ x, __hip_bfloat16* __restrict__ xb, int n4) {
    int i = blockIdx.x * blockDim.x + threadIdx.x;
    int stride = gridDim.x * blockDim.x;
    for (; i < n4; i += stride) {
        float4 v = ((const float4*)x)[i];
        ushort4 o;
        o.x = __bfloat16_as_ushort(__float2bfloat16(v.x));
        o.y = __bfloat16_as_ushort(__float2bfloat16(v.y));
        o.z = __bfloat16_as_ushort(__float2bfloat16(v.z));
        o.w = __bfloat16_as_ushort(__float2bfloat16(v.w));
        ((ushort4*)xb)[i] = o;
    }
}

__device__ inline float ldf(const float* p) { return *p; }
__device__ inline float ldf(const __hip_bfloat16* p) { return __bfloat162float(*p); }

// One wave per node, lane = channel. 256 threads = 4 nodes/block.
// h = relu(mean_{j in N(i)} X_j @ Wl + bl + X_i @ Wr)
// FINAL=0: out bf16 [N,64].  FINAL=1: out f32 [N] = h . Wc + bc.
template <typename TIN, bool FINAL>
__global__ __launch_bounds__(256) void sage_kernel(
    const TIN* __restrict__ X, const int* __restrict__ csr,
    const int* __restrict__ offs,
    const float* __restrict__ Wl, const float* __restrict__ bl,
    const float* __restrict__ Wr, const float* __restrict__ Wc,
    const float* __restrict__ bc, void* __restrict__ outp, int n)
{
    const int lane = threadIdx.x & 63;
    const int wid  = threadIdx.x >> 6;
    const int node = blockIdx.x * 4 + wid;
    __shared__ float smem[4][2][C];

    bool active = (node < n);
    if (active) {
        int start = offs[node];
        int dcount = offs[node + 1] - start;
        float acc = 0.f;
        int k = 0;
        // 16-deep batches: 16 outstanding row-gathers per wave.
        for (; k + 16 <= dcount; k += 16) {
            int idx[16];
            #pragma unroll
            for (int j = 0; j < 16; ++j) idx[j] = csr[start + k + j];
            float v[16];
            #pragma unroll
            for (int j = 0; j < 16; ++j) v[j] = ldf(&X[(size_t)idx[j] * C + lane]);
            #pragma unroll
            for (int j = 0; j < 16; ++j) acc += v[j];
        }
        for (; k + 4 <= dcount; k += 4) {
            int i0 = csr[start + k + 0];
            int i1 = csr[start + k + 1];
            int i2 = csr[start + k + 2];
            int i3 = csr[start + k + 3];
            float a0 = ldf(&X[(size_t)i0 * C + lane]);
            float a1 = ldf(&X[(size_t)i1 * C + lane]);
            float a2 = ldf(&X[(size_t)i2 * C + lane]);
            float a3 = ldf(&X[(size_t)i3 * C + lane]);
            acc += a0; acc += a1; acc += a2; acc += a3;
        }
        for (; k < dcount; ++k)
            acc += ldf(&X[(size_t)csr[start + k] * C + lane]);
        smem[wid][0][lane] = acc * (1.0f / fmaxf((float)dcount, 1.0f));
        smem[wid][1][lane] = ldf(&X[(size_t)node * C + lane]);
    }
    __syncthreads();
    if (!active) return;

    float o = bl[lane];
    #pragma unroll 8
    for (int kk = 0; kk < C; ++kk) {
        o += smem[wid][0][kk] * Wl[kk * C + lane];
        o += smem[wid][1][kk] * Wr[kk * C + lane];
    }
    o = fmaxf(o, 0.f);

    if (!FINAL) {
        ((__hip_bfloat16*)outp)[(size_t)node * C + lane] = __float2bfloat16(o);
    } else {
        float p = o * Wc[lane];
        #pragma unroll
        for (int off = 32; off >= 1; off >>= 1) p += __shfl_xor(p, off, 64);
        if (lane == 0) ((float*)outp)[node] = p + bc[0];
    }
}

extern "C" void kernel_launch(void* const* d_in, const int* in_sizes, int n_in,
                              void* d_out, int out_size, void* d_ws, size_t ws_size,
                              hipStream_t stream) {
    const float* x   = (const float*)d_in[0];
    const int*   ei  = (const int*)d_in[1];
    const float* Wl1 = (const float*)d_in[2];
    const float* bl1 = (const float*)d_in[3];
    const float* Wr1 = (const float*)d_in[4];
    const float* Wl2 = (const float*)d_in[5];
    const float* bl2 = (const float*)d_in[6];
    const float* Wr2 = (const float*)d_in[7];
    const float* Wc  = (const float*)d_in[8];
    const float* bc  = (const float*)d_in[9];
    float* out = (float*)d_out;

    const int N = in_sizes[0] / C;
    const int E = in_sizes[1] / 2;
    const int nb = (N + 1023) / 1024;

    char* ws = (char*)d_ws;
    size_t off = 0;
    int* deg    = (int*)(ws + off); off += align256((size_t)N * 4);
    int* cursor = (int*)(ws + off); off += align256((size_t)N * 4);
    int* offs   = (int*)(ws + off); off += align256((size_t)(N + 1) * 4);
    int* bsum   = (int*)(ws + off); off += align256((size_t)nb * 4);
    int* csr    = (int*)(ws + off); off += align256((size_t)E * 4);
    __hip_bfloat16* h1 = (__hip_bfloat16*)(ws + off); off += align256((size_t)N * C * 2);
    if (off > ws_size) return;   // fail loudly rather than corrupt neighbors

    __hip_bfloat16* xb = (__hip_bfloat16*)(ws + off);
    const bool use_xb = (off + align256((size_t)N * C * 2)) <= ws_size;

    // zero deg + cursor (contiguous leading regions)
    hipMemsetAsync(d_ws, 0, align256((size_t)N * 4) + (size_t)N * 4, stream);

    const int blk = 256;
    count_kernel<<<1024, blk, 0, stream>>>(ei, deg, E);
    scan1_kernel<<<nb, 1024, 0, stream>>>(deg, offs, bsum, N);
    scan2_kernel<<<1, 1024, 0, stream>>>(bsum, offs, nb, N);
    scan3_kernel<<<(N + 255) / 256, 256, 0, stream>>>(offs, bsum, N);
    fill_kernel<<<1024, blk, 0, stream>>>(ei, offs, cursor, csr, E);

    const int node_grid = (N + 3) / 4;
    if (use_xb) {
        cvt_kernel<<<1024, blk, 0, stream>>>(x, xb, N * C / 4);
        sage_kernel<__hip_bfloat16, false><<<node_grid, blk, 0, stream>>>(
            xb, csr, offs, Wl1, bl1, Wr1, nullptr, nullptr, h1, N);
    } else {
        sage_kernel<float, false><<<node_grid, blk, 0, stream>>>(
            x, csr, offs, Wl1, bl1, Wr1, nullptr, nullptr, h1, N);
    }
    sage_kernel<__hip_bfloat16, true><<<node_grid, blk, 0, stream>>>(
        h1, csr, offs, Wl2, bl2, Wr2, Wc, bc, out, N);
}

// Round 4
// 331.404 us; speedup vs baseline: 1.6285x; 1.5277x over previous
//
#include <hip/hip_runtime.h>

// GraphSAGE 2-layer + classifier on MI355X.
// Round 4: fp16 feature path, 8-rows/instr vectorized gather (no cross-lane
// reduce), MFMA (16x16x32 f16) for both linear layers, fused head.
// N=100000, E=1600000, C=HID=64.  N % 32 == 0.
//
// ws: deg(N int, reused as fill cursor) | offs(N+1) | bsum | csr(E) |
//     h1(N*64 fp16) | xh(N*64 fp16) | wp(4 mats packed fp16, 32KB)
// total ~32.8 MB  (proven ws_size >= 33.2 MB from round-3 FETCH evidence)

#define C 64

typedef _Float16 half8 __attribute__((ext_vector_type(8)));
typedef float f32x4 __attribute__((ext_vector_type(4)));

static inline size_t align256(size_t x) { return (x + 255) & ~(size_t)255; }

// ---------------- CSR build ----------------
__global__ void count_kernel(const int* __restrict__ ei, int* __restrict__ deg, int E) {
    const int4* d4 = (const int4*)(ei + E);        // row 1 = dst
    int nE4 = E >> 2;
    int stride = gridDim.x * blockDim.x;
    for (int i = blockIdx.x * blockDim.x + threadIdx.x; i < nE4; i += stride) {
        int4 d = d4[i];
        atomicAdd(&deg[d.x], 1);
        atomicAdd(&deg[d.y], 1);
        atomicAdd(&deg[d.z], 1);
        atomicAdd(&deg[d.w], 1);
    }
    for (int e = (nE4 << 2) + blockIdx.x * blockDim.x + threadIdx.x; e < E; e += stride)
        atomicAdd(&deg[ei[E + e]], 1);
}

__global__ __launch_bounds__(1024) void scan1_kernel(const int* __restrict__ deg,
                                                     int* __restrict__ offs,
                                                     int* __restrict__ bsum, int n) {
    __shared__ int wsum[16];
    const int lane = threadIdx.x & 63;
    const int wid  = threadIdx.x >> 6;
    int i = blockIdx.x * 1024 + threadIdx.x;
    int v = (i < n) ? deg[i] : 0;
    int s = v;
    #pragma unroll
    for (int off = 1; off < 64; off <<= 1) {
        int t = __shfl_up(s, off, 64);
        if (lane >= off) s += t;
    }
    if (lane == 63) wsum[wid] = s;
    __syncthreads();
    int wprefix = 0;
    for (int w = 0; w < wid; ++w) wprefix += wsum[w];
    if (i < n) offs[i] = wprefix + (s - v);
    if (threadIdx.x == 0) {
        int tot = 0;
        #pragma unroll
        for (int w = 0; w < 16; ++w) tot += wsum[w];
        bsum[blockIdx.x] = tot;
    }
}

__global__ __launch_bounds__(1024) void scan2_kernel(int* __restrict__ bsum,
                                                     int* __restrict__ offs, int nb, int n) {
    __shared__ int wsum[16];
    const int lane = threadIdx.x & 63;
    const int wid  = threadIdx.x >> 6;
    int v = ((int)threadIdx.x < nb) ? bsum[threadIdx.x] : 0;
    int s = v;
    #pragma unroll
    for (int off = 1; off < 64; off <<= 1) {
        int t = __shfl_up(s, off, 64);
        if (lane >= off) s += t;
    }
    if (lane == 63) wsum[wid] = s;
    __syncthreads();
    int wprefix = 0;
    for (int w = 0; w < wid; ++w) wprefix += wsum[w];
    if ((int)threadIdx.x < nb) bsum[threadIdx.x] = wprefix + (s - v);
    if (threadIdx.x == 0) {
        int tot = 0;
        #pragma unroll
        for (int w = 0; w < 16; ++w) tot += wsum[w];
        offs[n] = tot;
    }
}

__global__ void scan3_kernel(int* __restrict__ offs, const int* __restrict__ bsum, int n) {
    int i = blockIdx.x * blockDim.x + threadIdx.x;
    if (i < n) offs[i] += bsum[i >> 10];
}

__global__ void fill_kernel(const int* __restrict__ ei, const int* __restrict__ offs,
                            int* __restrict__ cursor, int* __restrict__ csr, int E) {
    const int4* s4 = (const int4*)ei;
    const int4* d4 = (const int4*)(ei + E);
    int nE4 = E >> 2;
    int stride = gridDim.x * blockDim.x;
    for (int i = blockIdx.x * blockDim.x + threadIdx.x; i < nE4; i += stride) {
        int4 s = s4[i];
        int4 d = d4[i];
        int p;
        p = atomicAdd(&cursor[d.x], 1); csr[offs[d.x] + p] = s.x;
        p = atomicAdd(&cursor[d.y], 1); csr[offs[d.y] + p] = s.y;
        p = atomicAdd(&cursor[d.z], 1); csr[offs[d.z] + p] = s.z;
        p = atomicAdd(&cursor[d.w], 1); csr[offs[d.w] + p] = s.w;
    }
    for (int e = (nE4 << 2) + blockIdx.x * blockDim.x + threadIdx.x; e < E; e += stride) {
        int d = ei[E + e];
        int p = atomicAdd(&cursor[d], 1);
        csr[offs[d] + p] = ei[e];
    }
}

// ---------------- conversions ----------------
// f32 [N*C] -> fp16, 8 elems/thread/iter
__global__ void cvtx_kernel(const float* __restrict__ x, _Float16* __restrict__ xh, int n8) {
    int stride = gridDim.x * blockDim.x;
    for (int i = blockIdx.x * blockDim.x + threadIdx.x; i < n8; i += stride) {
        const float4* p = (const float4*)x + (size_t)i * 2;
        float4 a = p[0], b = p[1];
        half8 h;
        h[0] = (_Float16)a.x; h[1] = (_Float16)a.y; h[2] = (_Float16)a.z; h[3] = (_Float16)a.w;
        h[4] = (_Float16)b.x; h[5] = (_Float16)b.y; h[6] = (_Float16)b.z; h[7] = (_Float16)b.w;
        ((half8*)xh)[i] = h;
    }
}

// Pack 4 64x64 f32 weight mats into MFMA B-fragment order (fp16):
// wp[mat][tile(4)][step(2)][lane(64)][j(8)],  B[k][n]: k = step*32 + (lane>>4)*8 + j,
// n = tile*16 + (lane&15).
__global__ void wpack_kernel(const float* __restrict__ W0, const float* __restrict__ W1,
                             const float* __restrict__ W2, const float* __restrict__ W3,
                             _Float16* __restrict__ wp) {
    int t = blockIdx.x * blockDim.x + threadIdx.x;
    if (t >= 2048) return;
    int lane = t & 63, step = (t >> 6) & 1, tile = (t >> 7) & 3, mat = t >> 9;
    const float* W = (mat == 0) ? W0 : (mat == 1) ? W1 : (mat == 2) ? W2 : W3;
    int col = tile * 16 + (lane & 15);
    int k0  = step * 32 + ((lane >> 4) << 3);
    half8 h;
    #pragma unroll
    for (int j = 0; j < 8; ++j) h[j] = (_Float16)W[(k0 + j) * C + col];
    ((half8*)wp)[t] = h;
}

// ---------------- fused SAGE layer ----------------
// Block = 256 threads = 4 waves = 32 nodes. Gather: wave handles 8 nodes,
// lane = (slot<<3)|sub: slot = node, sub = 16B chunk (8 channels). Each lane
// owns its (node, 8ch) f32 accumulator -> no cross-lane reduce.
// MLP: h = relu(agg @ Wl + bl + x @ Wr) via mfma_f32_16x16x32_f16.
// FINAL=0: write h to h1 (fp16). FINAL=1: out[i] = h . Wc + bc (f32).
template <bool FINAL>
__global__ __launch_bounds__(256) void sage_kernel(
    const _Float16* __restrict__ Xh, const int* __restrict__ csr,
    const int* __restrict__ offs,
    const _Float16* __restrict__ wpL, const _Float16* __restrict__ wpR,
    const float* __restrict__ bl,
    const float* __restrict__ Wc, const float* __restrict__ bc,
    void* __restrict__ outp, int n)
{
    const int lane = threadIdx.x & 63;
    const int wid  = threadIdx.x >> 6;
    const int base = blockIdx.x * 32;
    __shared__ _Float16 Aagg[32][72];   // 64 data halves + pad (stride 144B)
    __shared__ float Opart[2][2][16];

    // ---- gather ----
    const int slot = lane >> 3;
    const int sub  = lane & 7;
    const int node = base + wid * 8 + slot;
    float acc[8] = {0.f,0.f,0.f,0.f,0.f,0.f,0.f,0.f};
    int dcount = 0;
    if (node < n) {
        int start = offs[node];
        dcount = offs[node + 1] - start;
        int k = 0;
        for (; k + 2 <= dcount; k += 2) {
            int i0 = csr[start + k];
            int i1 = csr[start + k + 1];
            half8 v0 = *(const half8*)(Xh + ((size_t)i0 << 6) + (sub << 3));
            half8 v1 = *(const half8*)(Xh + ((size_t)i1 << 6) + (sub << 3));
            #pragma unroll
            for (int j = 0; j < 8; ++j) acc[j] += (float)v0[j];
            #pragma unroll
            for (int j = 0; j < 8; ++j) acc[j] += (float)v1[j];
        }
        if (k < dcount) {
            int i0 = csr[start + k];
            half8 v0 = *(const half8*)(Xh + ((size_t)i0 << 6) + (sub << 3));
            #pragma unroll
            for (int j = 0; j < 8; ++j) acc[j] += (float)v0[j];
        }
    }
    float inv = 1.0f / fmaxf((float)dcount, 1.0f);
    half8 hv;
    #pragma unroll
    for (int j = 0; j < 8; ++j) hv[j] = (_Float16)(acc[j] * inv);
    *(half8*)&Aagg[wid * 8 + slot][sub * 8] = hv;
    __syncthreads();

    // ---- MFMA MLP ----
    const int Mtile = wid >> 1;          // 0..1 (16-node half)
    const int pair  = wid & 1;           // col-tile pair
    const int row16 = lane & 15;
    const int kg    = lane >> 4;         // 0..3
    const int myrow = base + Mtile * 16 + row16;
    const int srow  = (myrow < n) ? myrow : 0;

    half8 ag0 = *(const half8*)&Aagg[Mtile * 16 + row16][kg * 8];
    half8 ag1 = *(const half8*)&Aagg[Mtile * 16 + row16][32 + kg * 8];
    const _Float16* xrow = Xh + ((size_t)srow << 6);
    half8 xi0 = *(const half8*)(xrow + kg * 8);
    half8 xi1 = *(const half8*)(xrow + 32 + kg * 8);

    float ptot[4] = {0.f, 0.f, 0.f, 0.f};
    #pragma unroll
    for (int q = 0; q < 2; ++q) {
        const int ct = pair * 2 + q;
        const half8* BL = (const half8*)(wpL + (size_t)ct * 1024);
        const half8* BR = (const half8*)(wpR + (size_t)ct * 1024);
        half8 b0 = BL[lane];
        half8 b1 = BL[64 + lane];
        half8 b2 = BR[lane];
        half8 b3 = BR[64 + lane];
        f32x4 cacc = {0.f, 0.f, 0.f, 0.f};
        cacc = __builtin_amdgcn_mfma_f32_16x16x32_f16(ag0, b0, cacc, 0, 0, 0);
        cacc = __builtin_amdgcn_mfma_f32_16x16x32_f16(ag1, b1, cacc, 0, 0, 0);
        cacc = __builtin_amdgcn_mfma_f32_16x16x32_f16(xi0, b2, cacc, 0, 0, 0);
        cacc = __builtin_amdgcn_mfma_f32_16x16x32_f16(xi1, b3, cacc, 0, 0, 0);

        const int col = ct * 16 + row16;
        const float bias = bl[col];
        if (!FINAL) {
            _Float16* h1 = (_Float16*)outp;
            #pragma unroll
            for (int j = 0; j < 4; ++j) {
                int r = base + Mtile * 16 + kg * 4 + j;
                if (r < n) {
                    float v = fmaxf(cacc[j] + bias, 0.f);
                    h1[((size_t)r << 6) + col] = (_Float16)v;
                }
            }
        } else {
            const float wc = Wc[col];
            float p[4];
            #pragma unroll
            for (int j = 0; j < 4; ++j) p[j] = fmaxf(cacc[j] + bias, 0.f) * wc;
            #pragma unroll
            for (int off = 1; off < 16; off <<= 1) {
                #pragma unroll
                for (int j = 0; j < 4; ++j) p[j] += __shfl_xor(p[j], off, 64);
            }
            #pragma unroll
            for (int j = 0; j < 4; ++j) ptot[j] += p[j];
        }
    }

    if (FINAL) {
        if (row16 == 0) {
            #pragma unroll
            for (int j = 0; j < 4; ++j) Opart[Mtile][pair][kg * 4 + j] = ptot[j];
        }
        __syncthreads();
        const int tid = threadIdx.x;
        if (tid < 32) {
            int Mt = tid >> 4, r = tid & 15;
            int gr = base + Mt * 16 + r;
            if (gr < n)
                ((float*)outp)[gr] = Opart[Mt][0][r] + Opart[Mt][1][r] + bc[0];
        }
    }
}

extern "C" void kernel_launch(void* const* d_in, const int* in_sizes, int n_in,
                              void* d_out, int out_size, void* d_ws, size_t ws_size,
                              hipStream_t stream) {
    const float* x   = (const float*)d_in[0];
    const int*   ei  = (const int*)d_in[1];
    const float* Wl1 = (const float*)d_in[2];
    const float* bl1 = (const float*)d_in[3];
    const float* Wr1 = (const float*)d_in[4];
    const float* Wl2 = (const float*)d_in[5];
    const float* bl2 = (const float*)d_in[6];
    const float* Wr2 = (const float*)d_in[7];
    const float* Wc  = (const float*)d_in[8];
    const float* bc  = (const float*)d_in[9];
    float* out = (float*)d_out;

    const int N = in_sizes[0] / C;
    const int E = in_sizes[1] / 2;
    const int nb = (N + 1023) / 1024;

    char* ws = (char*)d_ws;
    size_t off = 0;
    int* deg  = (int*)(ws + off); off += align256((size_t)N * 4);       // also fill cursor
    int* offs = (int*)(ws + off); off += align256((size_t)(N + 1) * 4);
    int* bsum = (int*)(ws + off); off += align256((size_t)nb * 4);
    int* csr  = (int*)(ws + off); off += align256((size_t)E * 4);
    _Float16* h1 = (_Float16*)(ws + off); off += align256((size_t)N * C * 2);
    _Float16* xh = (_Float16*)(ws + off); off += align256((size_t)N * C * 2);
    _Float16* wp = (_Float16*)(ws + off); off += align256((size_t)2048 * 8 * 2);
    if (off > ws_size) return;   // fail loudly rather than corrupt neighbors

    const int blk = 256;
    hipMemsetAsync(deg, 0, (size_t)N * 4, stream);
    cvtx_kernel<<<2048, blk, 0, stream>>>(x, xh, N * C / 8);
    wpack_kernel<<<8, blk, 0, stream>>>(Wl1, Wr1, Wl2, Wr2, wp);
    count_kernel<<<1024, blk, 0, stream>>>(ei, deg, E);
    scan1_kernel<<<nb, 1024, 0, stream>>>(deg, offs, bsum, N);
    hipMemsetAsync(deg, 0, (size_t)N * 4, stream);   // deg becomes fill cursor
    scan2_kernel<<<1, 1024, 0, stream>>>(bsum, offs, nb, N);
    scan3_kernel<<<(N + 255) / 256, 256, 0, stream>>>(offs, bsum, N);
    fill_kernel<<<1024, blk, 0, stream>>>(ei, offs, deg, csr, E);

    const int node_grid = (N + 31) / 32;
    sage_kernel<false><<<node_grid, blk, 0, stream>>>(
        xh, csr, offs, wp, wp + 4096, bl1, nullptr, nullptr, h1, N);
    sage_kernel<true><<<node_grid, blk, 0, stream>>>(
        h1, csr, offs, wp + 8192, wp + 12288, bl2, Wc, bc, out, N);
}

// Round 5
// 266.376 us; speedup vs baseline: 2.0261x; 1.2441x over previous
//
#include <hip/hip_runtime.h>

// GraphSAGE 2-layer + classifier on MI355X.
// Round 5: rank-trick CSR build (no atomics in fill, no cursor), ILP-batched
// count atomics, 4-deep sage gather ILP. fp16 MFMA MLP as round 4.
// N=100000, E=1600000, C=HID=64.
//
// ws: deg(N) | offs(N+1) | bsum | csr(E) | h1(N*64 fp16, first 6.4MB aliased
//     by rank(E int) pre-sage) | xh(N*64 fp16) | wp(32KB)   total ~32.9 MB

#define C 64

typedef _Float16 half8 __attribute__((ext_vector_type(8)));
typedef float f32x4 __attribute__((ext_vector_type(4)));

static inline size_t align256(size_t x) { return (x + 255) & ~(size_t)255; }

// ---------------- CSR build ----------------
// count + rank in one pass: p = arrival order of edge within its dst bucket.
__global__ void count_kernel(const int* __restrict__ ei, int* __restrict__ deg,
                             int* __restrict__ rank, int E) {
    const int4* d4 = (const int4*)(ei + E);        // row 1 = dst
    int nE4 = E >> 2;
    int stride = gridDim.x * blockDim.x;
    for (int i = blockIdx.x * blockDim.x + threadIdx.x; i < nE4; i += stride) {
        int4 d = d4[i];
        int4 r;
        r.x = atomicAdd(&deg[d.x], 1);   // 4 independent atomics in flight
        r.y = atomicAdd(&deg[d.y], 1);
        r.z = atomicAdd(&deg[d.z], 1);
        r.w = atomicAdd(&deg[d.w], 1);
        ((int4*)rank)[i] = r;            // coalesced
    }
    for (int e = (nE4 << 2) + blockIdx.x * blockDim.x + threadIdx.x; e < E; e += stride)
        rank[e] = atomicAdd(&deg[ei[E + e]], 1);
}

__global__ __launch_bounds__(1024) void scan1_kernel(const int* __restrict__ deg,
                                                     int* __restrict__ offs,
                                                     int* __restrict__ bsum, int n) {
    __shared__ int wsum[16];
    const int lane = threadIdx.x & 63;
    const int wid  = threadIdx.x >> 6;
    int i = blockIdx.x * 1024 + threadIdx.x;
    int v = (i < n) ? deg[i] : 0;
    int s = v;
    #pragma unroll
    for (int off = 1; off < 64; off <<= 1) {
        int t = __shfl_up(s, off, 64);
        if (lane >= off) s += t;
    }
    if (lane == 63) wsum[wid] = s;
    __syncthreads();
    int wprefix = 0;
    for (int w = 0; w < wid; ++w) wprefix += wsum[w];
    if (i < n) offs[i] = wprefix + (s - v);
    if (threadIdx.x == 0) {
        int tot = 0;
        #pragma unroll
        for (int w = 0; w < 16; ++w) tot += wsum[w];
        bsum[blockIdx.x] = tot;
    }
}

__global__ __launch_bounds__(1024) void scan2_kernel(int* __restrict__ bsum,
                                                     int* __restrict__ offs, int nb, int n) {
    __shared__ int wsum[16];
    const int lane = threadIdx.x & 63;
    const int wid  = threadIdx.x >> 6;
    int v = ((int)threadIdx.x < nb) ? bsum[threadIdx.x] : 0;
    int s = v;
    #pragma unroll
    for (int off = 1; off < 64; off <<= 1) {
        int t = __shfl_up(s, off, 64);
        if (lane >= off) s += t;
    }
    if (lane == 63) wsum[wid] = s;
    __syncthreads();
    int wprefix = 0;
    for (int w = 0; w < wid; ++w) wprefix += wsum[w];
    if ((int)threadIdx.x < nb) bsum[threadIdx.x] = wprefix + (s - v);
    if (threadIdx.x == 0) {
        int tot = 0;
        #pragma unroll
        for (int w = 0; w < 16; ++w) tot += wsum[w];
        offs[n] = tot;
    }
}

__global__ void scan3_kernel(int* __restrict__ offs, const int* __restrict__ bsum, int n) {
    int i = blockIdx.x * blockDim.x + threadIdx.x;
    if (i < n) offs[i] += bsum[i >> 10];
}

// No atomics: csr[offs[d] + rank[e]] = src[e]; stores are fire-and-forget.
__global__ void fill_kernel(const int* __restrict__ ei, const int* __restrict__ offs,
                            const int* __restrict__ rank, int* __restrict__ csr, int E) {
    const int4* s4 = (const int4*)ei;
    const int4* d4 = (const int4*)(ei + E);
    const int4* r4 = (const int4*)rank;
    int nE4 = E >> 2;
    int stride = gridDim.x * blockDim.x;
    for (int i = blockIdx.x * blockDim.x + threadIdx.x; i < nE4; i += stride) {
        int4 s = s4[i];
        int4 d = d4[i];
        int4 r = r4[i];
        int o0 = offs[d.x];
        int o1 = offs[d.y];
        int o2 = offs[d.z];
        int o3 = offs[d.w];
        csr[o0 + r.x] = s.x;
        csr[o1 + r.y] = s.y;
        csr[o2 + r.z] = s.z;
        csr[o3 + r.w] = s.w;
    }
    for (int e = (nE4 << 2) + blockIdx.x * blockDim.x + threadIdx.x; e < E; e += stride)
        csr[offs[ei[E + e]] + rank[e]] = ei[e];
}

// ---------------- conversions ----------------
__global__ void cvtx_kernel(const float* __restrict__ x, _Float16* __restrict__ xh, int n8) {
    int stride = gridDim.x * blockDim.x;
    for (int i = blockIdx.x * blockDim.x + threadIdx.x; i < n8; i += stride) {
        const float4* p = (const float4*)x + (size_t)i * 2;
        float4 a = p[0], b = p[1];
        half8 h;
        h[0] = (_Float16)a.x; h[1] = (_Float16)a.y; h[2] = (_Float16)a.z; h[3] = (_Float16)a.w;
        h[4] = (_Float16)b.x; h[5] = (_Float16)b.y; h[6] = (_Float16)b.z; h[7] = (_Float16)b.w;
        ((half8*)xh)[i] = h;
    }
}

// Pack 4 64x64 f32 weight mats into MFMA B-fragment order (fp16):
// wp[mat][tile(4)][step(2)][lane(64)][j(8)], B[k][n]: k = step*32+(lane>>4)*8+j,
// n = tile*16 + (lane&15).
__global__ void wpack_kernel(const float* __restrict__ W0, const float* __restrict__ W1,
                             const float* __restrict__ W2, const float* __restrict__ W3,
                             _Float16* __restrict__ wp) {
    int t = blockIdx.x * blockDim.x + threadIdx.x;
    if (t >= 2048) return;
    int lane = t & 63, step = (t >> 6) & 1, tile = (t >> 7) & 3, mat = t >> 9;
    const float* W = (mat == 0) ? W0 : (mat == 1) ? W1 : (mat == 2) ? W2 : W3;
    int col = tile * 16 + (lane & 15);
    int k0  = step * 32 + ((lane >> 4) << 3);
    half8 h;
    #pragma unroll
    for (int j = 0; j < 8; ++j) h[j] = (_Float16)W[(k0 + j) * C + col];
    ((half8*)wp)[t] = h;
}

// ---------------- fused SAGE layer ----------------
// Block = 256 = 4 waves = 32 nodes. Gather: lane = (slot<<3)|sub, slot=node,
// sub=16B chunk; each lane owns (node, 8ch) f32 acc. 4-deep row ILP.
// MLP: h = relu(agg @ Wl + bl + x @ Wr) via mfma_f32_16x16x32_f16.
template <bool FINAL>
__global__ __launch_bounds__(256) void sage_kernel(
    const _Float16* __restrict__ Xh, const int* __restrict__ csr,
    const int* __restrict__ offs,
    const _Float16* __restrict__ wpL, const _Float16* __restrict__ wpR,
    const float* __restrict__ bl,
    const float* __restrict__ Wc, const float* __restrict__ bc,
    void* __restrict__ outp, int n)
{
    const int lane = threadIdx.x & 63;
    const int wid  = threadIdx.x >> 6;
    const int base = blockIdx.x * 32;
    __shared__ _Float16 Aagg[32][72];
    __shared__ float Opart[2][2][16];

    // ---- gather ----
    const int slot = lane >> 3;
    const int sub  = lane & 7;
    const int node = base + wid * 8 + slot;
    float acc[8] = {0.f,0.f,0.f,0.f,0.f,0.f,0.f,0.f};
    int dcount = 0;
    if (node < n) {
        int start = offs[node];
        dcount = offs[node + 1] - start;
        int k = 0;
        for (; k + 4 <= dcount; k += 4) {
            int i0 = csr[start + k + 0];
            int i1 = csr[start + k + 1];
            int i2 = csr[start + k + 2];
            int i3 = csr[start + k + 3];
            half8 v0 = *(const half8*)(Xh + ((size_t)i0 << 6) + (sub << 3));
            half8 v1 = *(const half8*)(Xh + ((size_t)i1 << 6) + (sub << 3));
            half8 v2 = *(const half8*)(Xh + ((size_t)i2 << 6) + (sub << 3));
            half8 v3 = *(const half8*)(Xh + ((size_t)i3 << 6) + (sub << 3));
            #pragma unroll
            for (int j = 0; j < 8; ++j) acc[j] += (float)v0[j];
            #pragma unroll
            for (int j = 0; j < 8; ++j) acc[j] += (float)v1[j];
            #pragma unroll
            for (int j = 0; j < 8; ++j) acc[j] += (float)v2[j];
            #pragma unroll
            for (int j = 0; j < 8; ++j) acc[j] += (float)v3[j];
        }
        for (; k < dcount; ++k) {
            int i0 = csr[start + k];
            half8 v0 = *(const half8*)(Xh + ((size_t)i0 << 6) + (sub << 3));
            #pragma unroll
            for (int j = 0; j < 8; ++j) acc[j] += (float)v0[j];
        }
    }
    float inv = 1.0f / fmaxf((float)dcount, 1.0f);
    half8 hv;
    #pragma unroll
    for (int j = 0; j < 8; ++j) hv[j] = (_Float16)(acc[j] * inv);
    *(half8*)&Aagg[wid * 8 + slot][sub * 8] = hv;
    __syncthreads();

    // ---- MFMA MLP ----
    const int Mtile = wid >> 1;
    const int pair  = wid & 1;
    const int row16 = lane & 15;
    const int kg    = lane >> 4;
    const int myrow = base + Mtile * 16 + row16;
    const int srow  = (myrow < n) ? myrow : 0;

    half8 ag0 = *(const half8*)&Aagg[Mtile * 16 + row16][kg * 8];
    half8 ag1 = *(const half8*)&Aagg[Mtile * 16 + row16][32 + kg * 8];
    const _Float16* xrow = Xh + ((size_t)srow << 6);
    half8 xi0 = *(const half8*)(xrow + kg * 8);
    half8 xi1 = *(const half8*)(xrow + 32 + kg * 8);

    float ptot[4] = {0.f, 0.f, 0.f, 0.f};
    #pragma unroll
    for (int q = 0; q < 2; ++q) {
        const int ct = pair * 2 + q;
        const half8* BL = (const half8*)(wpL + (size_t)ct * 1024);
        const half8* BR = (const half8*)(wpR + (size_t)ct * 1024);
        half8 b0 = BL[lane];
        half8 b1 = BL[64 + lane];
        half8 b2 = BR[lane];
        half8 b3 = BR[64 + lane];
        f32x4 cacc = {0.f, 0.f, 0.f, 0.f};
        cacc = __builtin_amdgcn_mfma_f32_16x16x32_f16(ag0, b0, cacc, 0, 0, 0);
        cacc = __builtin_amdgcn_mfma_f32_16x16x32_f16(ag1, b1, cacc, 0, 0, 0);
        cacc = __builtin_amdgcn_mfma_f32_16x16x32_f16(xi0, b2, cacc, 0, 0, 0);
        cacc = __builtin_amdgcn_mfma_f32_16x16x32_f16(xi1, b3, cacc, 0, 0, 0);

        const int col = ct * 16 + row16;
        const float bias = bl[col];
        if (!FINAL) {
            _Float16* h1 = (_Float16*)outp;
            #pragma unroll
            for (int j = 0; j < 4; ++j) {
                int r = base + Mtile * 16 + kg * 4 + j;
                if (r < n) {
                    float v = fmaxf(cacc[j] + bias, 0.f);
                    h1[((size_t)r << 6) + col] = (_Float16)v;
                }
            }
        } else {
            const float wc = Wc[col];
            float p[4];
            #pragma unroll
            for (int j = 0; j < 4; ++j) p[j] = fmaxf(cacc[j] + bias, 0.f) * wc;
            #pragma unroll
            for (int off = 1; off < 16; off <<= 1) {
                #pragma unroll
                for (int j = 0; j < 4; ++j) p[j] += __shfl_xor(p[j], off, 64);
            }
            #pragma unroll
            for (int j = 0; j < 4; ++j) ptot[j] += p[j];
        }
    }

    if (FINAL) {
        if (row16 == 0) {
            #pragma unroll
            for (int j = 0; j < 4; ++j) Opart[Mtile][pair][kg * 4 + j] = ptot[j];
        }
        __syncthreads();
        const int tid = threadIdx.x;
        if (tid < 32) {
            int Mt = tid >> 4, r = tid & 15;
            int gr = base + Mt * 16 + r;
            if (gr < n)
                ((float*)outp)[gr] = Opart[Mt][0][r] + Opart[Mt][1][r] + bc[0];
        }
    }
}

extern "C" void kernel_launch(void* const* d_in, const int* in_sizes, int n_in,
                              void* d_out, int out_size, void* d_ws, size_t ws_size,
                              hipStream_t stream) {
    const float* x   = (const float*)d_in[0];
    const int*   ei  = (const int*)d_in[1];
    const float* Wl1 = (const float*)d_in[2];
    const float* bl1 = (const float*)d_in[3];
    const float* Wr1 = (const float*)d_in[4];
    const float* Wl2 = (const float*)d_in[5];
    const float* bl2 = (const float*)d_in[6];
    const float* Wr2 = (const float*)d_in[7];
    const float* Wc  = (const float*)d_in[8];
    const float* bc  = (const float*)d_in[9];
    float* out = (float*)d_out;

    const int N = in_sizes[0] / C;
    const int E = in_sizes[1] / 2;
    const int nb = (N + 1023) / 1024;

    char* ws = (char*)d_ws;
    size_t off = 0;
    int* deg  = (int*)(ws + off); off += align256((size_t)N * 4);
    int* offs = (int*)(ws + off); off += align256((size_t)(N + 1) * 4);
    int* bsum = (int*)(ws + off); off += align256((size_t)nb * 4);
    int* csr  = (int*)(ws + off); off += align256((size_t)E * 4);
    _Float16* h1 = (_Float16*)(ws + off); off += align256((size_t)N * C * 2);
    _Float16* xh = (_Float16*)(ws + off); off += align256((size_t)N * C * 2);
    _Float16* wp = (_Float16*)(ws + off); off += align256((size_t)2048 * 8 * 2);
    if (off > ws_size) return;   // fail loudly rather than corrupt neighbors

    // rank aliases h1 (disjoint lifetimes: rank dies before sage1 writes h1)
    int* rank = (int*)h1;

    const int blk = 256;
    const int egrid = (E / 4 + blk - 1) / blk;   // 1 int4 per thread
    hipMemsetAsync(deg, 0, (size_t)N * 4, stream);
    cvtx_kernel<<<2048, blk, 0, stream>>>(x, xh, N * C / 8);
    wpack_kernel<<<8, blk, 0, stream>>>(Wl1, Wr1, Wl2, Wr2, wp);
    count_kernel<<<egrid, blk, 0, stream>>>(ei, deg, rank, E);
    scan1_kernel<<<nb, 1024, 0, stream>>>(deg, offs, bsum, N);
    scan2_kernel<<<1, 1024, 0, stream>>>(bsum, offs, nb, N);
    scan3_kernel<<<(N + 255) / 256, 256, 0, stream>>>(offs, bsum, N);
    fill_kernel<<<egrid, blk, 0, stream>>>(ei, offs, rank, csr, E);

    const int node_grid = (N + 31) / 32;
    sage_kernel<false><<<node_grid, blk, 0, stream>>>(
        xh, csr, offs, wp, wp + 4096, bl1, nullptr, nullptr, h1, N);
    sage_kernel<true><<<node_grid, blk, 0, stream>>>(
        h1, csr, offs, wp + 8192, wp + 12288, bl2, Wc, bc, out, N);
}

// Round 7
// 259.651 us; speedup vs baseline: 2.0786x; 1.0259x over previous
//
#include <hip/hip_runtime.h>

// GraphSAGE 2-layer + classifier on MI355X.
// Round 7 (= round 6 resubmit after infra timeout): line-padded degree
// histogram (1 counter / 64B line) to break atomic line ping-pong;
// cvt+wpack+count merged into one prep kernel; scan3 folded into fill/sage.
// N=100000, E=1600000, C=HID=64.
//
// ws: offs(N+1) | bsum(nb) | {deg_pad(16N) -> csr(E)} | h1(N*64 fp16,
//     rank(E) aliases first half pre-sage) | xh(N*64 fp16) | wp(32KB)
// total ~32.5 MB (proven ws_size >= 33.2 MB)

#define C 64

typedef _Float16 half8 __attribute__((ext_vector_type(8)));
typedef float f32x4 __attribute__((ext_vector_type(4)));

static inline size_t align256(size_t x) { return (x + 255) & ~(size_t)255; }

// ---------------- prep: count+rank | cvt x->fp16 | pack weights ----------------
__device__ void count_part(const int* __restrict__ ei, int* __restrict__ deg_pad,
                           int* __restrict__ rank, int E, int bid) {
    int i = bid * 256 + (int)threadIdx.x;
    int nE4 = E >> 2;
    if (i < nE4) {
        int4 d = ((const int4*)(ei + E))[i];     // row 1 = dst
        int4 r;
        r.x = atomicAdd(&deg_pad[d.x << 4], 1);  // one counter per 64B line
        r.y = atomicAdd(&deg_pad[d.y << 4], 1);
        r.z = atomicAdd(&deg_pad[d.z << 4], 1);
        r.w = atomicAdd(&deg_pad[d.w << 4], 1);
        ((int4*)rank)[i] = r;                    // coalesced
    }
    if (bid == 0 && threadIdx.x == 0) {
        for (int e = nE4 << 2; e < E; ++e)
            rank[e] = atomicAdd(&deg_pad[ei[E + e] << 4], 1);
    }
}

__device__ void cvt_part(const float* __restrict__ x, _Float16* __restrict__ xh,
                         int n8, int bid) {
    int i = bid * 256 + (int)threadIdx.x;
    if (i < n8) {
        const float4* p = (const float4*)x + (size_t)i * 2;
        float4 a = p[0], b = p[1];
        half8 h;
        h[0] = (_Float16)a.x; h[1] = (_Float16)a.y; h[2] = (_Float16)a.z; h[3] = (_Float16)a.w;
        h[4] = (_Float16)b.x; h[5] = (_Float16)b.y; h[6] = (_Float16)b.z; h[7] = (_Float16)b.w;
        ((half8*)xh)[i] = h;
    }
}

// wp[mat][tile(4)][step(2)][lane(64)][j(8)], B[k][n]: k = step*32+(lane>>4)*8+j,
// n = tile*16 + (lane&15).
__device__ void wpack_part(const float* __restrict__ W0, const float* __restrict__ W1,
                           const float* __restrict__ W2, const float* __restrict__ W3,
                           _Float16* __restrict__ wp, int bid) {
    int t = bid * 256 + (int)threadIdx.x;
    if (t >= 2048) return;
    int lane = t & 63, step = (t >> 6) & 1, tile = (t >> 7) & 3, mat = t >> 9;
    const float* W = (mat == 0) ? W0 : (mat == 1) ? W1 : (mat == 2) ? W2 : W3;
    int col = tile * 16 + (lane & 15);
    int k0  = step * 32 + ((lane >> 4) << 3);
    half8 h;
    #pragma unroll
    for (int j = 0; j < 8; ++j) h[j] = (_Float16)W[(k0 + j) * C + col];
    ((half8*)wp)[t] = h;
}

__global__ __launch_bounds__(256) void prep_kernel(
    const int* __restrict__ ei, int* __restrict__ deg_pad, int* __restrict__ rank, int E,
    const float* __restrict__ x, _Float16* __restrict__ xh, int n8,
    const float* __restrict__ W0, const float* __restrict__ W1,
    const float* __restrict__ W2, const float* __restrict__ W3,
    _Float16* __restrict__ wp, int egrid, int cgrid)
{
    int bid = blockIdx.x;
    if (bid < egrid)            count_part(ei, deg_pad, rank, E, bid);
    else if (bid < egrid + cgrid) cvt_part(x, xh, n8, bid - egrid);
    else                        wpack_part(W0, W1, W2, W3, wp, bid - egrid - cgrid);
}

// ---------------- scan (2 kernels; block prefixes applied lazily) ----------------
__global__ __launch_bounds__(1024) void scan1_kernel(const int* __restrict__ deg_pad,
                                                     int* __restrict__ offs,
                                                     int* __restrict__ bsum, int n) {
    __shared__ int wsum[16];
    const int lane = threadIdx.x & 63;
    const int wid  = threadIdx.x >> 6;
    int i = blockIdx.x * 1024 + threadIdx.x;
    int v = (i < n) ? deg_pad[(size_t)i << 4] : 0;
    int s = v;
    #pragma unroll
    for (int off = 1; off < 64; off <<= 1) {
        int t = __shfl_up(s, off, 64);
        if (lane >= off) s += t;
    }
    if (lane == 63) wsum[wid] = s;
    __syncthreads();
    int wprefix = 0;
    for (int w = 0; w < wid; ++w) wprefix += wsum[w];
    if (i < n) offs[i] = wprefix + (s - v);
    if (threadIdx.x == 0) {
        int tot = 0;
        #pragma unroll
        for (int w = 0; w < 16; ++w) tot += wsum[w];
        bsum[blockIdx.x] = tot;
    }
}

__global__ __launch_bounds__(1024) void scan2_kernel(int* __restrict__ bsum,
                                                     int* __restrict__ offs, int nb, int n) {
    __shared__ int wsum[16];
    const int lane = threadIdx.x & 63;
    const int wid  = threadIdx.x >> 6;
    int v = ((int)threadIdx.x < nb) ? bsum[threadIdx.x] : 0;
    int s = v;
    #pragma unroll
    for (int off = 1; off < 64; off <<= 1) {
        int t = __shfl_up(s, off, 64);
        if (lane >= off) s += t;
    }
    if (lane == 63) wsum[wid] = s;
    __syncthreads();
    int wprefix = 0;
    for (int w = 0; w < wid; ++w) wprefix += wsum[w];
    if ((int)threadIdx.x < nb) bsum[threadIdx.x] = wprefix + (s - v);
    if (threadIdx.x == 0) {
        int tot = 0;
        #pragma unroll
        for (int w = 0; w < 16; ++w) tot += wsum[w];
        offs[n] = tot;   // grand total (bsum already folded in)
    }
}

// ---------------- fill (no atomics; bsum applied on the fly) ----------------
__global__ __launch_bounds__(256) void fill_kernel(
    const int* __restrict__ ei, const int* __restrict__ offs,
    const int* __restrict__ bsum, const int* __restrict__ rank,
    int* __restrict__ csr, int E)
{
    int i = blockIdx.x * 256 + (int)threadIdx.x;
    int nE4 = E >> 2;
    if (i < nE4) {
        int4 s = ((const int4*)ei)[i];
        int4 d = ((const int4*)(ei + E))[i];
        int4 r = ((const int4*)rank)[i];
        int o0 = offs[d.x] + bsum[d.x >> 10];
        int o1 = offs[d.y] + bsum[d.y >> 10];
        int o2 = offs[d.z] + bsum[d.z >> 10];
        int o3 = offs[d.w] + bsum[d.w >> 10];
        csr[o0 + r.x] = s.x;
        csr[o1 + r.y] = s.y;
        csr[o2 + r.z] = s.z;
        csr[o3 + r.w] = s.w;
    }
    if (blockIdx.x == 0 && threadIdx.x == 0) {
        for (int e = nE4 << 2; e < E; ++e) {
            int d = ei[E + e];
            csr[offs[d] + bsum[d >> 10] + rank[e]] = ei[e];
        }
    }
}

// ---------------- fused SAGE layer ----------------
// Block = 256 = 4 waves = 32 nodes. Gather: lane = (slot<<3)|sub, slot=node,
// sub=16B chunk; each lane owns (node, 8ch) f32 acc. 4-deep row ILP.
// MLP: h = relu(agg @ Wl + bl + x @ Wr) via mfma_f32_16x16x32_f16.
template <bool FINAL>
__global__ __launch_bounds__(256) void sage_kernel(
    const _Float16* __restrict__ Xh, const int* __restrict__ csr,
    const int* __restrict__ offs, const int* __restrict__ bsum,
    const _Float16* __restrict__ wpL, const _Float16* __restrict__ wpR,
    const float* __restrict__ bl,
    const float* __restrict__ Wc, const float* __restrict__ bc,
    void* __restrict__ outp, int n)
{
    const int lane = threadIdx.x & 63;
    const int wid  = threadIdx.x >> 6;
    const int base = blockIdx.x * 32;
    __shared__ _Float16 Aagg[32][72];
    __shared__ float Opart[2][2][16];

    // ---- gather ----
    const int slot = lane >> 3;
    const int sub  = lane & 7;
    const int node = base + wid * 8 + slot;
    float acc[8] = {0.f,0.f,0.f,0.f,0.f,0.f,0.f,0.f};
    int dcount = 0;
    if (node < n) {
        int start = offs[node] + bsum[node >> 10];
        int end   = (node + 1 == n) ? offs[n]
                                    : offs[node + 1] + bsum[(node + 1) >> 10];
        dcount = end - start;
        int k = 0;
        for (; k + 4 <= dcount; k += 4) {
            int i0 = csr[start + k + 0];
            int i1 = csr[start + k + 1];
            int i2 = csr[start + k + 2];
            int i3 = csr[start + k + 3];
            half8 v0 = *(const half8*)(Xh + ((size_t)i0 << 6) + (sub << 3));
            half8 v1 = *(const half8*)(Xh + ((size_t)i1 << 6) + (sub << 3));
            half8 v2 = *(const half8*)(Xh + ((size_t)i2 << 6) + (sub << 3));
            half8 v3 = *(const half8*)(Xh + ((size_t)i3 << 6) + (sub << 3));
            #pragma unroll
            for (int j = 0; j < 8; ++j) acc[j] += (float)v0[j];
            #pragma unroll
            for (int j = 0; j < 8; ++j) acc[j] += (float)v1[j];
            #pragma unroll
            for (int j = 0; j < 8; ++j) acc[j] += (float)v2[j];
            #pragma unroll
            for (int j = 0; j < 8; ++j) acc[j] += (float)v3[j];
        }
        for (; k < dcount; ++k) {
            int i0 = csr[start + k];
            half8 v0 = *(const half8*)(Xh + ((size_t)i0 << 6) + (sub << 3));
            #pragma unroll
            for (int j = 0; j < 8; ++j) acc[j] += (float)v0[j];
        }
    }
    float inv = 1.0f / fmaxf((float)dcount, 1.0f);
    half8 hv;
    #pragma unroll
    for (int j = 0; j < 8; ++j) hv[j] = (_Float16)(acc[j] * inv);
    *(half8*)&Aagg[wid * 8 + slot][sub * 8] = hv;
    __syncthreads();

    // ---- MFMA MLP ----
    const int Mtile = wid >> 1;
    const int pair  = wid & 1;
    const int row16 = lane & 15;
    const int kg    = lane >> 4;
    const int myrow = base + Mtile * 16 + row16;
    const int srow  = (myrow < n) ? myrow : 0;

    half8 ag0 = *(const half8*)&Aagg[Mtile * 16 + row16][kg * 8];
    half8 ag1 = *(const half8*)&Aagg[Mtile * 16 + row16][32 + kg * 8];
    const _Float16* xrow = Xh + ((size_t)srow << 6);
    half8 xi0 = *(const half8*)(xrow + kg * 8);
    half8 xi1 = *(const half8*)(xrow + 32 + kg * 8);

    float ptot[4] = {0.f, 0.f, 0.f, 0.f};
    #pragma unroll
    for (int q = 0; q < 2; ++q) {
        const int ct = pair * 2 + q;
        const half8* BL = (const half8*)(wpL + (size_t)ct * 1024);
        const half8* BR = (const half8*)(wpR + (size_t)ct * 1024);
        half8 b0 = BL[lane];
        half8 b1 = BL[64 + lane];
        half8 b2 = BR[lane];
        half8 b3 = BR[64 + lane];
        f32x4 cacc = {0.f, 0.f, 0.f, 0.f};
        cacc = __builtin_amdgcn_mfma_f32_16x16x32_f16(ag0, b0, cacc, 0, 0, 0);
        cacc = __builtin_amdgcn_mfma_f32_16x16x32_f16(ag1, b1, cacc, 0, 0, 0);
        cacc = __builtin_amdgcn_mfma_f32_16x16x32_f16(xi0, b2, cacc, 0, 0, 0);
        cacc = __builtin_amdgcn_mfma_f32_16x16x32_f16(xi1, b3, cacc, 0, 0, 0);

        const int col = ct * 16 + row16;
        const float bias = bl[col];
        if (!FINAL) {
            _Float16* h1 = (_Float16*)outp;
            #pragma unroll
            for (int j = 0; j < 4; ++j) {
                int r = base + Mtile * 16 + kg * 4 + j;
                if (r < n) {
                    float v = fmaxf(cacc[j] + bias, 0.f);
                    h1[((size_t)r << 6) + col] = (_Float16)v;
                }
            }
        } else {
            const float wc = Wc[col];
            float p[4];
            #pragma unroll
            for (int j = 0; j < 4; ++j) p[j] = fmaxf(cacc[j] + bias, 0.f) * wc;
            #pragma unroll
            for (int off = 1; off < 16; off <<= 1) {
                #pragma unroll
                for (int j = 0; j < 4; ++j) p[j] += __shfl_xor(p[j], off, 64);
            }
            #pragma unroll
            for (int j = 0; j < 4; ++j) ptot[j] += p[j];
        }
    }

    if (FINAL) {
        if (row16 == 0) {
            #pragma unroll
            for (int j = 0; j < 4; ++j) Opart[Mtile][pair][kg * 4 + j] = ptot[j];
        }
        __syncthreads();
        const int tid = threadIdx.x;
        if (tid < 32) {
            int Mt = tid >> 4, r = tid & 15;
            int gr = base + Mt * 16 + r;
            if (gr < n)
                ((float*)outp)[gr] = Opart[Mt][0][r] + Opart[Mt][1][r] + bc[0];
        }
    }
}

extern "C" void kernel_launch(void* const* d_in, const int* in_sizes, int n_in,
                              void* d_out, int out_size, void* d_ws, size_t ws_size,
                              hipStream_t stream) {
    const float* x   = (const float*)d_in[0];
    const int*   ei  = (const int*)d_in[1];
    const float* Wl1 = (const float*)d_in[2];
    const float* bl1 = (const float*)d_in[3];
    const float* Wr1 = (const float*)d_in[4];
    const float* Wl2 = (const float*)d_in[5];
    const float* bl2 = (const float*)d_in[6];
    const float* Wr2 = (const float*)d_in[7];
    const float* Wc  = (const float*)d_in[8];
    const float* bc  = (const float*)d_in[9];
    float* out = (float*)d_out;

    const int N = in_sizes[0] / C;
    const int E = in_sizes[1] / 2;
    const int nb = (N + 1023) / 1024;

    char* ws = (char*)d_ws;
    size_t off = 0;
    int* offs = (int*)(ws + off); off += align256((size_t)(N + 1) * 4);
    int* bsum = (int*)(ws + off); off += align256((size_t)nb * 4);
    // deg_pad (16N ints) and csr (E ints) share a region (disjoint lifetimes:
    // deg_pad dies after scan1; csr written by fill afterwards).
    size_t shared_sz = (size_t)E * 4 > (size_t)N * 64 ? (size_t)E * 4 : (size_t)N * 64;
    int* csr = (int*)(ws + off);
    int* deg_pad = csr; off += align256(shared_sz);
    _Float16* h1 = (_Float16*)(ws + off); off += align256((size_t)N * C * 2);
    _Float16* xh = (_Float16*)(ws + off); off += align256((size_t)N * C * 2);
    _Float16* wp = (_Float16*)(ws + off); off += align256((size_t)2048 * 8 * 2);
    if (off > ws_size) return;   // fail loudly rather than corrupt neighbors

    int* rank = (int*)h1;        // rank aliases h1 (dies before sage1 writes h1)

    const int blk = 256;
    const int egrid = (E / 4 + blk - 1) / blk;       // count blocks (int4/thread)
    const int n8 = N * C / 8;
    const int cgrid = (n8 + blk - 1) / blk;          // cvt blocks
    hipMemsetAsync(deg_pad, 0, (size_t)N * 64, stream);
    prep_kernel<<<egrid + cgrid + 8, blk, 0, stream>>>(
        ei, deg_pad, rank, E, x, xh, n8, Wl1, Wr1, Wl2, Wr2, wp, egrid, cgrid);
    scan1_kernel<<<nb, 1024, 0, stream>>>(deg_pad, offs, bsum, N);
    scan2_kernel<<<1, 1024, 0, stream>>>(bsum, offs, nb, N);
    fill_kernel<<<egrid, blk, 0, stream>>>(ei, offs, bsum, rank, csr, E);

    const int node_grid = (N + 31) / 32;
    sage_kernel<false><<<node_grid, blk, 0, stream>>>(
        xh, csr, offs, bsum, wp, wp + 4096, bl1, nullptr, nullptr, h1, N);
    sage_kernel<true><<<node_grid, blk, 0, stream>>>(
        h1, csr, offs, bsum, wp + 8192, wp + 12288, bl2, Wc, bc, out, N);
}